// Round 2
// baseline (794.937 us; speedup 1.0000x reference)
//
#include <hip/hip_runtime.h>
#include <stdint.h>

#define BATCH  65536
#define IN_DIM 1024
#define MASKED 512
#define HIDDEN 1024

typedef unsigned short u16;
typedef __bf16 bf16x8 __attribute__((ext_vector_type(8)));
typedef float  f32x4  __attribute__((ext_vector_type(4)));

typedef __attribute__((address_space(1))) void gvoid;
typedef __attribute__((address_space(3))) void lvoid;

__device__ __forceinline__ u16 f32_to_bf16(float f) {
    union { float f; uint32_t u; } v; v.f = f;
    uint32_t r = v.u + 0x7FFFu + ((v.u >> 16) & 1u);   // round-to-nearest-even
    return (u16)(r >> 16);
}

// ---------------------------------------------------------------------------
// prep: x (BATCH x IN_DIM f32) -> xm (BATCH x MASKED bf16)  [even columns]
// ---------------------------------------------------------------------------
__global__ void prep_xm(const float* __restrict__ x, u16* __restrict__ xm) {
    int idx = blockIdx.x * blockDim.x + threadIdx.x;   // 0 .. BATCH*IN_DIM/8
    const float4* xv = reinterpret_cast<const float4*>(x);
    float4 v0 = xv[idx * 2];
    float4 v1 = xv[idx * 2 + 1];
    ushort4 o;
    o.x = f32_to_bf16(v0.x);
    o.y = f32_to_bf16(v0.z);
    o.z = f32_to_bf16(v1.x);
    o.w = f32_to_bf16(v1.z);
    reinterpret_cast<ushort4*>(xm)[idx] = o;
}

// ---------------------------------------------------------------------------
// weight convert+transpose: W (K x N f32, row-major) -> Wt (N x K bf16)
// ---------------------------------------------------------------------------
__global__ void wconv(const float* __restrict__ W, u16* __restrict__ Wt,
                      int K, int N) {
    __shared__ float t[32][33];
    const int nbk = K / 32;
    const int bk = blockIdx.x % nbk;
    const int bn = blockIdx.x / nbk;
    const int tx = threadIdx.x & 31;
    const int ty = threadIdx.x >> 5;   // 0..7
    const int k0 = bk * 32, n0 = bn * 32;
    #pragma unroll
    for (int i = 0; i < 4; ++i)
        t[ty + i * 8][tx] = W[(int64_t)(k0 + ty + i * 8) * N + n0 + tx];
    __syncthreads();
    #pragma unroll
    for (int i = 0; i < 4; ++i)
        Wt[(int64_t)(n0 + ty + i * 8) * K + k0 + tx] = f32_to_bf16(t[tx][ty + i * 8]);
}

// ---------------------------------------------------------------------------
// GEMM: C(MxN) = A(MxK,bf16) @ Bt(NxK,bf16)^T + bias
// MODE 0: C = relu(.) -> bf16 Cb
// MODE 1: coupling epilogue: y[m][2n] = x[m][2n]; y[m][2n+1] = x[m][2n+1] + t
// 128x128 tile, BK=64, 256 threads (4 waves, 2x2), mfma 16x16x32 bf16
// XCD-aware bijective swizzle (T1): blocks sharing an A-panel land on one XCD.
// ---------------------------------------------------------------------------
template<int K, int N, int MODE>
__global__ __launch_bounds__(256, 5)   // 5 blocks/CU (LDS-limited: 5*32KB = 160KB)
void gemm_bt(const u16* __restrict__ A, const u16* __restrict__ Bt,
             const float* __restrict__ bias,
             u16* __restrict__ Cb,
             const float* __restrict__ X,
             float* __restrict__ Y) {
    constexpr int BK = 64;
    __shared__ u16 As[128 * BK];
    __shared__ u16 Bs[128 * BK];

    const int tid  = threadIdx.x;
    const int lane = tid & 63;
    const int w    = tid >> 6;      // wave 0..3
    const int wr   = w >> 1;        // wave row (0..1)
    const int wc   = w & 1;         // wave col (0..1)

    // T1: XCD swizzle. All grids here are multiples of 8 (NXCD), so the
    // simple chunked remap is bijective: XCD x owns tiles [x*cpx, (x+1)*cpx).
    const int nwg = gridDim.x;
    const int cpx = nwg >> 3;
    const int bid = (blockIdx.x & 7) * cpx + (blockIdx.x >> 3);

    constexpr int nbn = N / 128;
    const int bm = bid / nbn;
    const int bn = bid % nbn;
    const int m0 = bm * 128;
    const int n0 = bn * 128;

    f32x4 acc[4][4];
    #pragma unroll
    for (int i = 0; i < 4; ++i)
        #pragma unroll
        for (int j = 0; j < 4; ++j)
            acc[i][j] = f32x4{0.f, 0.f, 0.f, 0.f};

    // staging: wave w stages rows [w*32, w*32+32) in 4 calls of 8 rows each
    const int srow = lane >> 3;          // 0..7
    const int scol = (lane & 7) * 8;     // k element offset of this lane's 16B
    const u16* aptr = A  + (int64_t)(m0 + w * 32 + srow) * K + scol;
    const u16* bptr = Bt + (int64_t)(n0 + w * 32 + srow) * K + scol;

    for (int kt = 0; kt < K / BK; ++kt) {
        __syncthreads();   // previous tile fully consumed
        const int koff = kt * BK;
        #pragma unroll
        for (int c = 0; c < 4; ++c) {
            __builtin_amdgcn_global_load_lds(
                (gvoid*)(aptr + koff + c * 8 * K),
                (lvoid*)(&As[(w * 32 + c * 8) * BK]), 16, 0, 0);
            __builtin_amdgcn_global_load_lds(
                (gvoid*)(bptr + koff + c * 8 * K),
                (lvoid*)(&Bs[(w * 32 + c * 8) * BK]), 16, 0, 0);
        }
        __syncthreads();   // staged data visible (compiler drains vmcnt(0))

        #pragma unroll
        for (int kk = 0; kk < 2; ++kk) {
            bf16x8 a[4], b[4];
            #pragma unroll
            for (int i = 0; i < 4; ++i)
                a[i] = *reinterpret_cast<const bf16x8*>(
                    &As[(wr * 64 + i * 16 + (lane & 15)) * BK + kk * 32 + (lane >> 4) * 8]);
            #pragma unroll
            for (int j = 0; j < 4; ++j)
                b[j] = *reinterpret_cast<const bf16x8*>(
                    &Bs[(wc * 64 + j * 16 + (lane & 15)) * BK + kk * 32 + (lane >> 4) * 8]);
            #pragma unroll
            for (int i = 0; i < 4; ++i)
                #pragma unroll
                for (int j = 0; j < 4; ++j)
                    acc[i][j] = __builtin_amdgcn_mfma_f32_16x16x32_bf16(
                        a[i], b[j], acc[i][j], 0, 0, 0);
        }
    }

    // epilogue. C/D layout (m89-verified): col = lane&15, row = (lane>>4)*4 + reg
    const int cl = lane & 15;
    const int rg = (lane >> 4) * 4;
    #pragma unroll
    for (int j = 0; j < 4; ++j) {
        const int n  = n0 + wc * 64 + j * 16 + cl;
        const float bv = bias[n];
        #pragma unroll
        for (int i = 0; i < 4; ++i) {
            #pragma unroll
            for (int r = 0; r < 4; ++r) {
                const int m = m0 + wr * 64 + i * 16 + rg + r;
                float v = acc[i][j][r] + bv;
                if (MODE == 0) {
                    v = v > 0.f ? v : 0.f;
                    Cb[(int64_t)m * N + n] = f32_to_bf16(v);
                } else {
                    const int64_t p = (int64_t)m * IN_DIM + 2 * n;
                    float2 xv = *reinterpret_cast<const float2*>(&X[p]);
                    float2 o;
                    o.x = xv.x;          // even column: exact copy
                    o.y = xv.y + v;      // odd column: x + translation
                    *reinterpret_cast<float2*>(&Y[p]) = o;
                }
            }
        }
    }
}

// ---------------------------------------------------------------------------
extern "C" void kernel_launch(void* const* d_in, const int* in_sizes, int n_in,
                              void* d_out, int out_size, void* d_ws, size_t ws_size,
                              hipStream_t stream) {
    const float* x  = (const float*)d_in[0];
    const float* W1 = (const float*)d_in[1];
    const float* b1 = (const float*)d_in[2];
    const float* W2 = (const float*)d_in[3];
    const float* b2 = (const float*)d_in[4];
    const float* W3 = (const float*)d_in[5];
    const float* b3 = (const float*)d_in[6];
    float* y = (float*)d_out;

    char* ws = (char*)d_ws;
    // layout: h1 (128MB) | h2 (128MB, first 64MB aliased by xm) | W1t|W2t|W3t
    u16* h1  = (u16*)(ws);
    u16* h2  = (u16*)(ws + 134217728);
    u16* xm  = (u16*)(ws + 134217728);                 // dead before h2 is written
    u16* W1t = (u16*)(ws + 268435456);
    u16* W2t = (u16*)(ws + 268435456 + 1048576);
    u16* W3t = (u16*)(ws + 268435456 + 1048576 + 2097152);

    // 1) extract even columns -> bf16
    prep_xm<<<BATCH * IN_DIM / 8 / 256, 256, 0, stream>>>(x, xm);

    // 2) convert + transpose weights to bf16 N x K
    wconv<<<(MASKED / 32) * (HIDDEN / 32), 256, 0, stream>>>(W1, W1t, MASKED, HIDDEN);
    wconv<<<(HIDDEN / 32) * (HIDDEN / 32), 256, 0, stream>>>(W2, W2t, HIDDEN, HIDDEN);
    wconv<<<(HIDDEN / 32) * ((IN_DIM - MASKED) / 32), 256, 0, stream>>>(W3, W3t, HIDDEN, IN_DIM - MASKED);

    // 3) three GEMMs
    gemm_bt<MASKED, HIDDEN, 0><<<(BATCH / 128) * (HIDDEN / 128), 256, 0, stream>>>(
        xm, W1t, b1, h1, nullptr, nullptr);
    gemm_bt<HIDDEN, HIDDEN, 0><<<(BATCH / 128) * (HIDDEN / 128), 256, 0, stream>>>(
        h1, W2t, b2, h2, nullptr, nullptr);
    gemm_bt<HIDDEN, IN_DIM - MASKED, 1><<<(BATCH / 128) * ((IN_DIM - MASKED) / 128), 256, 0, stream>>>(
        h2, W3t, b3, nullptr, x, y);
}

// Round 3
// 469.752 us; speedup vs baseline: 1.6922x; 1.6922x over previous
//
#include <hip/hip_runtime.h>
#include <stdint.h>

#define BATCH  65536
#define IN_DIM 1024
#define MASKED 512
#define HIDDEN 1024

typedef unsigned short u16;
typedef __bf16 bf16x8 __attribute__((ext_vector_type(8)));
typedef float  f32x4  __attribute__((ext_vector_type(4)));

typedef __attribute__((address_space(1))) void gvoid;
typedef __attribute__((address_space(3))) void lvoid;

__device__ __forceinline__ u16 f32_to_bf16(float f) {
    union { float f; uint32_t u; } v; v.f = f;
    uint32_t r = v.u + 0x7FFFu + ((v.u >> 16) & 1u);   // round-to-nearest-even
    return (u16)(r >> 16);
}

// ---------------------------------------------------------------------------
// prep: x (BATCH x IN_DIM f32) -> xm (BATCH x MASKED bf16)  [even columns]
// ---------------------------------------------------------------------------
__global__ void prep_xm(const float* __restrict__ x, u16* __restrict__ xm) {
    int idx = blockIdx.x * blockDim.x + threadIdx.x;   // 0 .. BATCH*IN_DIM/8
    const float4* xv = reinterpret_cast<const float4*>(x);
    float4 v0 = xv[idx * 2];
    float4 v1 = xv[idx * 2 + 1];
    ushort4 o;
    o.x = f32_to_bf16(v0.x);
    o.y = f32_to_bf16(v0.z);
    o.z = f32_to_bf16(v1.x);
    o.w = f32_to_bf16(v1.z);
    reinterpret_cast<ushort4*>(xm)[idx] = o;
}

// ---------------------------------------------------------------------------
// weight convert+transpose: W (K x N f32, row-major) -> Wt (N x K bf16)
// ---------------------------------------------------------------------------
__global__ void wconv(const float* __restrict__ W, u16* __restrict__ Wt,
                      int K, int N) {
    __shared__ float t[32][33];
    const int nbk = K / 32;
    const int bk = blockIdx.x % nbk;
    const int bn = blockIdx.x / nbk;
    const int tx = threadIdx.x & 31;
    const int ty = threadIdx.x >> 5;   // 0..7
    const int k0 = bk * 32, n0 = bn * 32;
    #pragma unroll
    for (int i = 0; i < 4; ++i)
        t[ty + i * 8][tx] = W[(int64_t)(k0 + ty + i * 8) * N + n0 + tx];
    __syncthreads();
    #pragma unroll
    for (int i = 0; i < 4; ++i)
        Wt[(int64_t)(n0 + ty + i * 8) * K + k0 + tx] = f32_to_bf16(t[tx][ty + i * 8]);
}

// ---------------------------------------------------------------------------
// GEMM: C(MxN) = A(MxK,bf16) @ Bt(NxK,bf16)^T + bias
// MODE 0: C = relu(.) -> bf16 Cb
// MODE 1: coupling epilogue: y[m][2n] = x[m][2n]; y[m][2n+1] = x[m][2n+1] + t
// 128x128 tile, BK=64, 256 threads (4 waves, 2x2), mfma 16x16x32 bf16
// XCD-aware bijective swizzle (T1).
// launch_bounds(256,4): 128 regs/thread budget >= 64 AGPR + ~60 VGPR (no
// spill; (256,5) forced a 96-reg budget and spilled the accumulator — R1).
// ---------------------------------------------------------------------------
template<int K, int N, int MODE>
__global__ __launch_bounds__(256, 4)
void gemm_bt(const u16* __restrict__ A, const u16* __restrict__ Bt,
             const float* __restrict__ bias,
             u16* __restrict__ Cb,
             const float* __restrict__ X,
             float* __restrict__ Y) {
    constexpr int BK = 64;
    __shared__ u16 As[128 * BK];
    __shared__ u16 Bs[128 * BK];

    const int tid  = threadIdx.x;
    const int lane = tid & 63;
    const int w    = tid >> 6;      // wave 0..3
    const int wr   = w >> 1;        // wave row (0..1)
    const int wc   = w & 1;         // wave col (0..1)

    // T1: XCD swizzle (grids here are all multiples of 8 -> bijective).
    const int nwg = gridDim.x;
    const int cpx = nwg >> 3;
    const int bid = (blockIdx.x & 7) * cpx + (blockIdx.x >> 3);

    constexpr int nbn = N / 128;
    const int bm = bid / nbn;
    const int bn = bid % nbn;
    const int m0 = bm * 128;
    const int n0 = bn * 128;

    f32x4 acc[4][4];
    #pragma unroll
    for (int i = 0; i < 4; ++i)
        #pragma unroll
        for (int j = 0; j < 4; ++j)
            acc[i][j] = f32x4{0.f, 0.f, 0.f, 0.f};

    // staging: wave w stages rows [w*32, w*32+32) in 4 calls of 8 rows each
    const int srow = lane >> 3;          // 0..7
    const int scol = (lane & 7) * 8;     // k element offset of this lane's 16B
    const u16* aptr = A  + (int64_t)(m0 + w * 32 + srow) * K + scol;
    const u16* bptr = Bt + (int64_t)(n0 + w * 32 + srow) * K + scol;

    for (int kt = 0; kt < K / BK; ++kt) {
        __syncthreads();   // previous tile fully consumed
        const int koff = kt * BK;
        #pragma unroll
        for (int c = 0; c < 4; ++c) {
            __builtin_amdgcn_global_load_lds(
                (gvoid*)(aptr + koff + c * 8 * K),
                (lvoid*)(&As[(w * 32 + c * 8) * BK]), 16, 0, 0);
            __builtin_amdgcn_global_load_lds(
                (gvoid*)(bptr + koff + c * 8 * K),
                (lvoid*)(&Bs[(w * 32 + c * 8) * BK]), 16, 0, 0);
        }
        __syncthreads();   // staged data visible (compiler drains vmcnt(0))

        #pragma unroll
        for (int kk = 0; kk < 2; ++kk) {
            bf16x8 a[4], b[4];
            #pragma unroll
            for (int i = 0; i < 4; ++i)
                a[i] = *reinterpret_cast<const bf16x8*>(
                    &As[(wr * 64 + i * 16 + (lane & 15)) * BK + kk * 32 + (lane >> 4) * 8]);
            #pragma unroll
            for (int j = 0; j < 4; ++j)
                b[j] = *reinterpret_cast<const bf16x8*>(
                    &Bs[(wc * 64 + j * 16 + (lane & 15)) * BK + kk * 32 + (lane >> 4) * 8]);
            #pragma unroll
            for (int i = 0; i < 4; ++i)
                #pragma unroll
                for (int j = 0; j < 4; ++j)
                    acc[i][j] = __builtin_amdgcn_mfma_f32_16x16x32_bf16(
                        a[i], b[j], acc[i][j], 0, 0, 0);
        }
    }

    // epilogue. C/D layout (m89-verified): col = lane&15, row = (lane>>4)*4 + reg
    const int cl = lane & 15;
    const int rg = (lane >> 4) * 4;
    #pragma unroll
    for (int j = 0; j < 4; ++j) {
        const int n  = n0 + wc * 64 + j * 16 + cl;
        const float bv = bias[n];
        #pragma unroll
        for (int i = 0; i < 4; ++i) {
            #pragma unroll
            for (int r = 0; r < 4; ++r) {
                const int m = m0 + wr * 64 + i * 16 + rg + r;
                float v = acc[i][j][r] + bv;
                if (MODE == 0) {
                    v = v > 0.f ? v : 0.f;
                    Cb[(int64_t)m * N + n] = f32_to_bf16(v);
                } else {
                    const int64_t p = (int64_t)m * IN_DIM + 2 * n;
                    float2 xv = *reinterpret_cast<const float2*>(&X[p]);
                    float2 o;
                    o.x = xv.x;          // even column: exact copy
                    o.y = xv.y + v;      // odd column: x + translation
                    *reinterpret_cast<float2*>(&Y[p]) = o;
                }
            }
        }
    }
}

// ---------------------------------------------------------------------------
extern "C" void kernel_launch(void* const* d_in, const int* in_sizes, int n_in,
                              void* d_out, int out_size, void* d_ws, size_t ws_size,
                              hipStream_t stream) {
    const float* x  = (const float*)d_in[0];
    const float* W1 = (const float*)d_in[1];
    const float* b1 = (const float*)d_in[2];
    const float* W2 = (const float*)d_in[3];
    const float* b2 = (const float*)d_in[4];
    const float* W3 = (const float*)d_in[5];
    const float* b3 = (const float*)d_in[6];
    float* y = (float*)d_out;

    char* ws = (char*)d_ws;
    // layout: h1 (128MB) | h2 (128MB, first 64MB aliased by xm) | W1t|W2t|W3t
    u16* h1  = (u16*)(ws);
    u16* h2  = (u16*)(ws + 134217728);
    u16* xm  = (u16*)(ws + 134217728);                 // dead before h2 is written
    u16* W1t = (u16*)(ws + 268435456);
    u16* W2t = (u16*)(ws + 268435456 + 1048576);
    u16* W3t = (u16*)(ws + 268435456 + 1048576 + 2097152);

    // 1) extract even columns -> bf16
    prep_xm<<<BATCH * IN_DIM / 8 / 256, 256, 0, stream>>>(x, xm);

    // 2) convert + transpose weights to bf16 N x K
    wconv<<<(MASKED / 32) * (HIDDEN / 32), 256, 0, stream>>>(W1, W1t, MASKED, HIDDEN);
    wconv<<<(HIDDEN / 32) * (HIDDEN / 32), 256, 0, stream>>>(W2, W2t, HIDDEN, HIDDEN);
    wconv<<<(HIDDEN / 32) * ((IN_DIM - MASKED) / 32), 256, 0, stream>>>(W3, W3t, HIDDEN, IN_DIM - MASKED);

    // 3) three GEMMs
    gemm_bt<MASKED, HIDDEN, 0><<<(BATCH / 128) * (HIDDEN / 128), 256, 0, stream>>>(
        xm, W1t, b1, h1, nullptr, nullptr);
    gemm_bt<HIDDEN, HIDDEN, 0><<<(BATCH / 128) * (HIDDEN / 128), 256, 0, stream>>>(
        h1, W2t, b2, h2, nullptr, nullptr);
    gemm_bt<HIDDEN, IN_DIM - MASKED, 1><<<(BATCH / 128) * ((IN_DIM - MASKED) / 128), 256, 0, stream>>>(
        h2, W3t, b3, nullptr, x, y);
}